// Round 12
// baseline (255.923 us; speedup 1.0000x reference)
//
#include <hip/hip_runtime.h>

#define AS1 __attribute__((address_space(1)))
#define AS3 __attribute__((address_space(3)))

using bf16x8  = __attribute__((ext_vector_type(8))) __bf16;
using floatx4 = __attribute__((ext_vector_type(4))) float;

#define SCQ 0.18033688f   // (1/sqrt(64)) * log2(e), folded into Q weights/bias

__device__ inline ushort f2b(float f) {
    __bf16 h = (__bf16)f;
    return __builtin_bit_cast(ushort, h);
}

// raw v_exp_f32 (2^x). Scores are O(+-20): no denorm/overflow handling needed.
__device__ inline float fexp2(float x) {
    float r;
    asm("v_exp_f32 %0, %1" : "=v"(r) : "v"(x));
    return r;
}

// packed f32x2 -> bf16x2 (lo = src0, hi = src1)
__device__ inline unsigned cvtpk_bf16(float lo, float hi) {
    unsigned r;
    asm("v_cvt_pk_bf16_f32 %0, %1, %2" : "=v"(r) : "v"(lo), "v"(hi));
    return r;
}
// a[32:63] <-> b[0:31]
__device__ inline void plswap32(unsigned& a, unsigned& b) {
    asm("v_permlane32_swap_b32 %0, %1" : "+v"(a), "+v"(b));
}
// a[16:31] <-> b[0:15], a[48:63] <-> b[32:47]
__device__ inline void plswap16(unsigned& a, unsigned& b) {
    asm("v_permlane16_swap_b32 %0, %1" : "+v"(a), "+v"(b));
}

// raw barriers for the attn pipeline (no implicit vmcnt(0) drain)
#define BARRIER_A() asm volatile("s_waitcnt lgkmcnt(0)\n\ts_barrier" ::: "memory")
#define BARRIER_B() asm volatile("s_barrier" ::: "memory")

// Build the PV A-fragment (keys base..base+31) from swapped-QK^T exp results.
__device__ inline bf16x8 pack_swap(floatx4 ej0, floatx4 ej1) {
    unsigned x0 = cvtpk_bf16(ej0[0], ej0[1]);
    unsigned x1 = cvtpk_bf16(ej0[2], ej0[3]);
    unsigned y0 = cvtpk_bf16(ej1[0], ej1[1]);
    unsigned y1 = cvtpk_bf16(ej1[2], ej1[3]);
    plswap32(x0, y0); plswap16(x0, y0);
    plswap32(x1, y1); plswap16(x1, y1);
    union { unsigned u[4]; bf16x8 v; } ua;
    ua.u[0] = x0; ua.u[1] = x1; ua.u[2] = y0; ua.u[3] = y1;
    return ua.v;
}

// ---------------- fused prep: f32->bf16 convert of x, + both weight transposes ----------------
__global__ void k_prep(const float* __restrict__ x, ushort* __restrict__ xb,
                       const float* __restrict__ wa, ushort* __restrict__ waT,
                       const float* __restrict__ wp, ushort* __restrict__ wpT)
{
    __shared__ float tile[32][33];
    int blk = blockIdx.x;
    if (blk < 8192) {
        int i = (blk * 256 + threadIdx.x) * 4;
        float4 v = *(const float4*)(x + i);
        ushort4 o;
        o.x = f2b(v.x); o.y = f2b(v.y); o.z = f2b(v.z); o.w = f2b(v.w);
        *(ushort4*)(xb + i) = o;
        return;
    }
    const float* in; ushort* out; int R, Ncol, bx, by; float scale; int scale_cols;
    if (blk < 11264) {
        int idx = blk - 8192;
        in = wa; out = waT; R = 1024; Ncol = 3072;
        bx = idx % 96; by = idx / 96; scale = SCQ; scale_cols = 1024;
    } else {
        int idx = blk - 11264;
        in = wp; out = wpT; R = 1024; Ncol = 1024;
        bx = idx % 32; by = idx / 32; scale = 1.0f; scale_cols = 0;
    }
    int tx = threadIdx.x & 31, ty = threadIdx.x >> 5;   // 32 x 8
    int c0 = bx * 32, r0 = by * 32;
    for (int i = 0; i < 32; i += 8)
        tile[ty + i][tx] = in[(size_t)(r0 + ty + i) * Ncol + c0 + tx];
    __syncthreads();
    for (int i = 0; i < 32; i += 8) {
        int n = c0 + ty + i;
        float v = tile[tx][ty + i];
        if (n < scale_cols) v *= scale;
        out[(size_t)n * R + r0 + tx] = f2b(v);
    }
}

// XCD-aware bijective swizzle of the linear block id (nwg % 8 == 0 for all our grids)
__device__ inline void xcd_swizzle(int& bx, int& by) {
    int gx = gridDim.x, lin = blockIdx.x + gx * blockIdx.y;
    int nwg = gx * gridDim.y;
    int swz = (lin & 7) * (nwg >> 3) + (lin >> 3);
    bx = swz % gx; by = swz / gx;
}

// ---------------- GEMM (proj): round-3 structure (BK=64, 128^2, 1-phase, (256,2)) ----------------
__global__ __launch_bounds__(256, 2) void k_gemm_bt(
    const ushort* __restrict__ A, const ushort* __restrict__ Bt,
    const float* __restrict__ bias, float* __restrict__ outv,
    int M, int N, int K)
{
    __shared__ __align__(16) ushort As[128 * 64];
    __shared__ __align__(16) ushort Bs[128 * 64];
    int tid = threadIdx.x;
    int bxs, bys; xcd_swizzle(bxs, bys);
    int m0 = bys * 128, n0 = bxs * 128;
    int lane = tid & 63;
    int wm = (tid >> 7) * 64;
    int wn = ((tid >> 6) & 1) * 64;
    int lr = lane & 15, quad = lane >> 4;

    floatx4 acc[4][4] = {};
    const ushort* ags[4]; const ushort* bgs[4]; int sdst[4];
    #pragma unroll
    for (int it = 0; it < 4; ++it) {
        int slot = tid + 256 * it;
        int row = slot >> 3, ch = slot & 7;
        ags[it] = A  + (size_t)(m0 + row) * K + ch * 8;
        bgs[it] = Bt + (size_t)(n0 + row) * K + ch * 8;
        sdst[it] = slot * 8;
    }

    for (int kt = 0; kt < K; kt += 64) {
        #pragma unroll
        for (int it = 0; it < 4; ++it) {
            __builtin_amdgcn_global_load_lds((const AS1 unsigned int*)(ags[it] + kt),
                                             (AS3 unsigned int*)&As[sdst[it]], 16, 0, 0);
            __builtin_amdgcn_global_load_lds((const AS1 unsigned int*)(bgs[it] + kt),
                                             (AS3 unsigned int*)&Bs[sdst[it]], 16, 0, 0);
        }
        asm volatile("s_waitcnt vmcnt(0)" ::: "memory");
        __syncthreads();
        bf16x8 af[4][2], bf[4][2];
        #pragma unroll
        for (int i = 0; i < 4; ++i) {
            af[i][0] = *(const bf16x8*)&As[(wm + 16 * i + lr) * 64 + quad * 8];
            af[i][1] = *(const bf16x8*)&As[(wm + 16 * i + lr) * 64 + 32 + quad * 8];
        }
        #pragma unroll
        for (int j = 0; j < 4; ++j) {
            bf[j][0] = *(const bf16x8*)&Bs[(wn + 16 * j + lr) * 64 + quad * 8];
            bf[j][1] = *(const bf16x8*)&Bs[(wn + 16 * j + lr) * 64 + 32 + quad * 8];
        }
        #pragma unroll
        for (int i = 0; i < 4; ++i)
            #pragma unroll
            for (int j = 0; j < 4; ++j) {
                acc[i][j] = __builtin_amdgcn_mfma_f32_16x16x32_bf16(af[i][0], bf[j][0], acc[i][j], 0, 0, 0);
                acc[i][j] = __builtin_amdgcn_mfma_f32_16x16x32_bf16(af[i][1], bf[j][1], acc[i][j], 0, 0, 0);
            }
        __syncthreads();
    }

    #pragma unroll
    for (int j = 0; j < 4; ++j) {
        int col = n0 + wn + 16 * j + lr;
        float bv = bias[col];
        #pragma unroll
        for (int i = 0; i < 4; ++i) {
            int row = m0 + wm + 16 * i + quad * 4;
            #pragma unroll
            for (int r = 0; r < 4; ++r)
                outv[(size_t)(row + r) * N + col] = acc[i][j][r] + bv;
        }
    }
}

// ---------------- QKV GEMM: round-3 structure (BK=64, 128^2, 1-phase, (256,2)) ----------------
// Epilogue routes: Q cols (0..1023)    -> qb[row][1024]           (row-major, Q only)
//                  K cols (1024..2047) -> kpk[bh][t][64] (packed) — contiguous 16KB/tile for attn
//                  V cols (2048..3071) -> vt[bh][d][2048] (transposed, as before)
__global__ __launch_bounds__(256, 2) void k_gemm_qkv(
    const ushort* __restrict__ A, const ushort* __restrict__ Bt,
    const float* __restrict__ bias, ushort* __restrict__ qb,
    ushort* __restrict__ kpk, ushort* __restrict__ vt)
{
    constexpr int K = 1024;
    __shared__ __align__(16) ushort As[128 * 64];
    __shared__ __align__(16) ushort Bs[128 * 64];
    int tid = threadIdx.x;
    int bxs, bys; xcd_swizzle(bxs, bys);
    int m0 = bys * 128, n0 = bxs * 128;
    int lane = tid & 63;
    int wm = (tid >> 7) * 64;
    int wn = ((tid >> 6) & 1) * 64;
    int lr = lane & 15, quad = lane >> 4;

    floatx4 acc[4][4] = {};
    const ushort* ags[4]; const ushort* bgs[4]; int sdst[4];
    #pragma unroll
    for (int it = 0; it < 4; ++it) {
        int slot = tid + 256 * it;
        int row = slot >> 3, ch = slot & 7;
        ags[it] = A  + (size_t)(m0 + row) * K + ch * 8;
        bgs[it] = Bt + (size_t)(n0 + row) * K + ch * 8;
        sdst[it] = slot * 8;
    }

    for (int kt = 0; kt < K; kt += 64) {
        #pragma unroll
        for (int it = 0; it < 4; ++it) {
            __builtin_amdgcn_global_load_lds((const AS1 unsigned int*)(ags[it] + kt),
                                             (AS3 unsigned int*)&As[sdst[it]], 16, 0, 0);
            __builtin_amdgcn_global_load_lds((const AS1 unsigned int*)(bgs[it] + kt),
                                             (AS3 unsigned int*)&Bs[sdst[it]], 16, 0, 0);
        }
        asm volatile("s_waitcnt vmcnt(0)" ::: "memory");
        __syncthreads();
        bf16x8 af[4][2], bf[4][2];
        #pragma unroll
        for (int i = 0; i < 4; ++i) {
            af[i][0] = *(const bf16x8*)&As[(wm + 16 * i + lr) * 64 + quad * 8];
            af[i][1] = *(const bf16x8*)&As[(wm + 16 * i + lr) * 64 + 32 + quad * 8];
        }
        #pragma unroll
        for (int j = 0; j < 4; ++j) {
            bf[j][0] = *(const bf16x8*)&Bs[(wn + 16 * j + lr) * 64 + quad * 8];
            bf[j][1] = *(const bf16x8*)&Bs[(wn + 16 * j + lr) * 64 + 32 + quad * 8];
        }
        #pragma unroll
        for (int i = 0; i < 4; ++i)
            #pragma unroll
            for (int j = 0; j < 4; ++j) {
                acc[i][j] = __builtin_amdgcn_mfma_f32_16x16x32_bf16(af[i][0], bf[j][0], acc[i][j], 0, 0, 0);
                acc[i][j] = __builtin_amdgcn_mfma_f32_16x16x32_bf16(af[i][1], bf[j][1], acc[i][j], 0, 0, 0);
            }
        __syncthreads();
    }

    int bb = m0 >> 11;   // batch index (blocks are 128-row, T=2048-aligned)
    #pragma unroll
    for (int j = 0; j < 4; ++j) {
        int col = n0 + wn + 16 * j + lr;
        float bv = bias[col];
        if (col < 1024) {
            bv *= SCQ;
            #pragma unroll
            for (int i = 0; i < 4; ++i) {
                int row = m0 + wm + 16 * i + quad * 4;
                #pragma unroll
                for (int r = 0; r < 4; ++r)
                    qb[(size_t)(row + r) * 1024 + col] = f2b(acc[i][j][r] + bv);
            }
        } else if (col < 2048) {
            int h = (col - 1024) >> 6, d = (col - 1024) & 63;
            ushort* kbase = kpk + ((size_t)(bb * 16 + h) * 2048) * 64 + d;
            #pragma unroll
            for (int i = 0; i < 4; ++i) {
                int t0 = (m0 + wm + 16 * i + quad * 4) & 2047;
                #pragma unroll
                for (int r = 0; r < 4; ++r)
                    kbase[(size_t)(t0 + r) * 64] = f2b(acc[i][j][r] + bv);
            }
        } else {
            int h = (col - 2048) >> 6, d = (col - 2048) & 63;
            ushort* vbase = vt + ((size_t)(bb * 16 + h) * 64 + d) * 2048;
            #pragma unroll
            for (int i = 0; i < 4; ++i) {
                int t0 = (m0 + wm + 16 * i + quad * 4) & 2047;
                ushort4 pk;
                ((ushort*)&pk)[0] = f2b(acc[i][j][0] + bv);
                ((ushort*)&pk)[1] = f2b(acc[i][j][1] + bv);
                ((ushort*)&pk)[2] = f2b(acc[i][j][2] + bv);
                ((ushort*)&pk)[3] = f2b(acc[i][j][3] + bv);
                *(ushort4*)&vbase[t0] = pk;
            }
        }
    }
}

// ---------------- causal flash attention (merged-2, raw barriers, packed K/V) ----------------
// Round-12: fused two-tile body interleaves MFMA and VALU phases:
// QKT_B -> exp/pack_B -> QKT_A -> PV_B -> exp/pack_A -> PV_A.
// exp_A's inputs have 10 intervening MFMAs to land (no result-latency stall),
// and exp_A's VALU overlaps PV_B's matrix-pipe drain. B is never diagonal in
// the fused path (kt <= ktdA < ktdB) so its mask test vanishes.
__device__ __forceinline__ void attn_tile(
    const ushort* __restrict__ Kb, const ushort* __restrict__ Vb,
    bf16x8 aq0, bf16x8 aq1, bf16x8 ones,
    floatx4 (&o)[4], floatx4& lacc,
    int kt, int ktd, int qrow, int lr, int quad, int c0, int c1)
{
    floatx4 s[4];
    __builtin_amdgcn_s_setprio(1);
    #pragma unroll
    for (int j = 0; j < 4; ++j) {
        const ushort* kr = &Kb[(16 * j + lr) * 64];
        bf16x8 bk0 = *(const bf16x8*)(kr + c0);
        bf16x8 bk1 = *(const bf16x8*)(kr + c1);
        floatx4 z = {};
        s[j] = __builtin_amdgcn_mfma_f32_16x16x32_bf16(bk0, aq0, z, 0, 0, 0);
        s[j] = __builtin_amdgcn_mfma_f32_16x16x32_bf16(bk1, aq1, s[j], 0, 0, 0);
    }
    __builtin_amdgcn_s_setprio(0);
    floatx4 e[4];
    if (kt == ktd) {
        int qa = qrow + lr;
        #pragma unroll
        for (int j = 0; j < 4; ++j)
            #pragma unroll
            for (int r = 0; r < 4; ++r)
                e[j][r] = ((kt * 64 + 16 * j + quad * 4 + r) > qa) ? 0.f : fexp2(s[j][r]);
    } else {
        #pragma unroll
        for (int j = 0; j < 4; ++j)
            #pragma unroll
            for (int r = 0; r < 4; ++r)
                e[j][r] = fexp2(s[j][r]);
    }
    bf16x8 ap0 = pack_swap(e[0], e[1]);
    bf16x8 ap1 = pack_swap(e[2], e[3]);
    __builtin_amdgcn_s_setprio(1);
    lacc = __builtin_amdgcn_mfma_f32_16x16x32_bf16(ap0, ones, lacc, 0, 0, 0);
    lacc = __builtin_amdgcn_mfma_f32_16x16x32_bf16(ap1, ones, lacc, 0, 0, 0);
    #pragma unroll
    for (int jd = 0; jd < 4; ++jd) {
        const ushort* vr = &Vb[(16 * jd + lr) * 64];
        bf16x8 bv0 = *(const bf16x8*)(vr + c0);
        bf16x8 bv1 = *(const bf16x8*)(vr + c1);
        o[jd] = __builtin_amdgcn_mfma_f32_16x16x32_bf16(ap0, bv0, o[jd], 0, 0, 0);
        o[jd] = __builtin_amdgcn_mfma_f32_16x16x32_bf16(ap1, bv1, o[jd], 0, 0, 0);
    }
    __builtin_amdgcn_s_setprio(0);
}

// fused both-tiles body (B non-diagonal; A may be diagonal at kt==ktdA)
__device__ __forceinline__ void attn_tile2(
    const ushort* __restrict__ Kb, const ushort* __restrict__ Vb,
    bf16x8 aqA0, bf16x8 aqA1, bf16x8 aqB0, bf16x8 aqB1, bf16x8 ones,
    floatx4 (&oA)[4], floatx4& laccA, floatx4 (&oB)[4], floatx4& laccB,
    int kt, int ktdA, int qrowA, int lr, int quad, int c0, int c1)
{
    // --- 1. S_B = K Q_B^T ---
    floatx4 s[4];
    __builtin_amdgcn_s_setprio(1);
    #pragma unroll
    for (int j = 0; j < 4; ++j) {
        const ushort* kr = &Kb[(16 * j + lr) * 64];
        bf16x8 bk0 = *(const bf16x8*)(kr + c0);
        bf16x8 bk1 = *(const bf16x8*)(kr + c1);
        floatx4 z = {};
        s[j] = __builtin_amdgcn_mfma_f32_16x16x32_bf16(bk0, aqB0, z, 0, 0, 0);
        s[j] = __builtin_amdgcn_mfma_f32_16x16x32_bf16(bk1, aqB1, s[j], 0, 0, 0);
    }
    __builtin_amdgcn_s_setprio(0);
    // --- 2-3. exp_B + pack_B (no mask: B is never diagonal here) ---
    floatx4 e[4];
    #pragma unroll
    for (int j = 0; j < 4; ++j)
        #pragma unroll
        for (int r = 0; r < 4; ++r)
            e[j][r] = fexp2(s[j][r]);
    bf16x8 apB0 = pack_swap(e[0], e[1]);
    bf16x8 apB1 = pack_swap(e[2], e[3]);
    // --- 4. S_A = K Q_A^T (s registers reused; apB live across) ---
    __builtin_amdgcn_s_setprio(1);
    #pragma unroll
    for (int j = 0; j < 4; ++j) {
        const ushort* kr = &Kb[(16 * j + lr) * 64];
        bf16x8 bk0 = *(const bf16x8*)(kr + c0);
        bf16x8 bk1 = *(const bf16x8*)(kr + c1);
        floatx4 z = {};
        s[j] = __builtin_amdgcn_mfma_f32_16x16x32_bf16(bk0, aqA0, z, 0, 0, 0);
        s[j] = __builtin_amdgcn_mfma_f32_16x16x32_bf16(bk1, aqA1, s[j], 0, 0, 0);
    }
    // --- 5. rowsum_B + PV_B (independent of s_A; keeps matrix pipe full) ---
    laccB = __builtin_amdgcn_mfma_f32_16x16x32_bf16(apB0, ones, laccB, 0, 0, 0);
    laccB = __builtin_amdgcn_mfma_f32_16x16x32_bf16(apB1, ones, laccB, 0, 0, 0);
    #pragma unroll
    for (int jd = 0; jd < 4; ++jd) {
        const ushort* vr = &Vb[(16 * jd + lr) * 64];
        bf16x8 bv0 = *(const bf16x8*)(vr + c0);
        bf16x8 bv1 = *(const bf16x8*)(vr + c1);
        oB[jd] = __builtin_amdgcn_mfma_f32_16x16x32_bf16(apB0, bv0, oB[jd], 0, 0, 0);
        oB[jd] = __builtin_amdgcn_mfma_f32_16x16x32_bf16(apB1, bv1, oB[jd], 0, 0, 0);
    }
    __builtin_amdgcn_s_setprio(0);
    // --- 6. exp_A (+mask at A's diagonal) + pack_A — overlaps PV_B drain ---
    if (kt == ktdA) {
        int qa = qrowA + lr;
        #pragma unroll
        for (int j = 0; j < 4; ++j)
            #pragma unroll
            for (int r = 0; r < 4; ++r)
                e[j][r] = ((kt * 64 + 16 * j + quad * 4 + r) > qa) ? 0.f : fexp2(s[j][r]);
    } else {
        #pragma unroll
        for (int j = 0; j < 4; ++j)
            #pragma unroll
            for (int r = 0; r < 4; ++r)
                e[j][r] = fexp2(s[j][r]);
    }
    bf16x8 apA0 = pack_swap(e[0], e[1]);
    bf16x8 apA1 = pack_swap(e[2], e[3]);
    // --- 7. rowsum_A + PV_A ---
    __builtin_amdgcn_s_setprio(1);
    laccA = __builtin_amdgcn_mfma_f32_16x16x32_bf16(apA0, ones, laccA, 0, 0, 0);
    laccA = __builtin_amdgcn_mfma_f32_16x16x32_bf16(apA1, ones, laccA, 0, 0, 0);
    #pragma unroll
    for (int jd = 0; jd < 4; ++jd) {
        const ushort* vr = &Vb[(16 * jd + lr) * 64];
        bf16x8 bv0 = *(const bf16x8*)(vr + c0);
        bf16x8 bv1 = *(const bf16x8*)(vr + c1);
        oA[jd] = __builtin_amdgcn_mfma_f32_16x16x32_bf16(apA0, bv0, oA[jd], 0, 0, 0);
        oA[jd] = __builtin_amdgcn_mfma_f32_16x16x32_bf16(apA1, bv1, oA[jd], 0, 0, 0);
    }
    __builtin_amdgcn_s_setprio(0);
}

__global__ __launch_bounds__(512, 4) void k_attn(const ushort* __restrict__ qb,
                                                 const ushort* __restrict__ kpk,
                                                 const ushort* __restrict__ vt,
                                                 ushort* __restrict__ out)
{
    constexpr int T = 2048, C = 1024;
    __shared__ __align__(16) ushort Ks[4][64 * 64];
    __shared__ __align__(16) ushort Vs[4][64 * 64];
    int tid = threadIdx.x;
    int lane = tid & 63, wave = tid >> 6;
    int lr = lane & 15, quad = lane >> 4, lk = quad * 8;

    int lin = blockIdx.x + 8 * blockIdx.y;             // grid (8, 64)
    int qt  = lin >> 6;                                // 0..7
    int bh  = lin & 63;
    int b = bh >> 4, h = bh & 15;
    const ushort* kg0 = kpk + (size_t)bh * T * 64;     // [t][d] packed per head
    const ushort* vg0 = vt + (size_t)bh * 64 * T;      // [d][t] packed per head

    int srow = tid >> 3;                     // key (K) / dim (V)
    int sg   = (tid & 7) ^ (srow & 7);       // XOR-swizzled source chunk
    int sdst = tid * 8;                      // linear LDS dest
    const ushort* kgs = kg0 + (size_t)srow * 64 + sg * 8;
    const ushort* vgs = vg0 + (size_t)srow * T + sg * 8;

    bf16x8 ones;
    #pragma unroll
    for (int i = 0; i < 8; ++i) ones[i] = (__bf16)1.0f;
    int c0 = (quad ^ (lr & 7)) * 8;
    int c1 = ((4 + quad) ^ (lr & 7)) * 8;

    int qtA = qt, qtB = 15 - qt;
    int qrowA = qtA * 128 + wave * 16;
    int qrowB = qtB * 128 + wave * 16;
    int ktdA = qrowA >> 6, ktdB = qrowB >> 6;
    const ushort* qpA = qb + ((size_t)(b * T + qrowA + lr)) * 1024 + h * 64;
    const ushort* qpB = qb + ((size_t)(b * T + qrowB + lr)) * 1024 + h * 64;
    bf16x8 aqA0 = *(const bf16x8*)(qpA + lk);
    bf16x8 aqA1 = *(const bf16x8*)(qpA + 32 + lk);
    bf16x8 aqB0 = *(const bf16x8*)(qpB + lk);
    bf16x8 aqB1 = *(const bf16x8*)(qpB + 32 + lk);
    floatx4 oA[4] = {}, oB[4] = {};
    floatx4 laccA = {}, laccB = {};
    int ktmax = 2 * qtB + 1;

    #pragma unroll
    for (int p = 0; p < 3; ++p) {
        __builtin_amdgcn_global_load_lds((const AS1 unsigned int*)(kgs + (size_t)p * 64 * 64),
                                         (AS3 unsigned int*)&Ks[p][sdst], 16, 0, 0);
        __builtin_amdgcn_global_load_lds((const AS1 unsigned int*)(vgs + p * 64),
                                         (AS3 unsigned int*)&Vs[p][sdst], 16, 0, 0);
    }

    for (int kt = 0; kt <= ktmax; ++kt) {
        BARRIER_A();
        if (kt + 3 <= ktmax) {
            int bidx = (kt + 3) & 3;
            __builtin_amdgcn_global_load_lds((const AS1 unsigned int*)(kgs + (size_t)(kt + 3) * 64 * 64),
                                             (AS3 unsigned int*)&Ks[bidx][sdst], 16, 0, 0);
            __builtin_amdgcn_global_load_lds((const AS1 unsigned int*)(vgs + (kt + 3) * 64),
                                             (AS3 unsigned int*)&Vs[bidx][sdst], 16, 0, 0);
            asm volatile("s_waitcnt vmcnt(6)" ::: "memory");
        } else if (kt + 2 <= ktmax) {
            asm volatile("s_waitcnt vmcnt(4)" ::: "memory");
        } else if (kt + 1 <= ktmax) {
            asm volatile("s_waitcnt vmcnt(2)" ::: "memory");
        } else {
            asm volatile("s_waitcnt vmcnt(0)" ::: "memory");
        }
        BARRIER_B();

        const ushort* Kb = Ks[kt & 3];
        const ushort* Vb = Vs[kt & 3];
        if (kt <= ktdA)
            attn_tile2(Kb, Vb, aqA0, aqA1, aqB0, aqB1, ones, oA, laccA, oB, laccB,
                       kt, ktdA, qrowA, lr, quad, c0, c1);
        else if (kt <= ktdB)
            attn_tile(Kb, Vb, aqB0, aqB1, ones, oB, laccB, kt, ktdB, qrowB, lr, quad, c0, c1);
    }

    #pragma unroll
    for (int r = 0; r < 4; ++r) {
        float invA = 1.0f / laccA[r];
        float invB = 1.0f / laccB[r];
        int rowA = b * T + qrowA + quad * 4 + r;
        int rowB = b * T + qrowB + quad * 4 + r;
        #pragma unroll
        for (int jd = 0; jd < 4; ++jd) {
            out[(size_t)rowA * C + h * 64 + 16 * jd + lr] = f2b(oA[jd][r] * invA);
            out[(size_t)rowB * C + h * 64 + 16 * jd + lr] = f2b(oB[jd][r] * invB);
        }
    }
}

extern "C" void kernel_launch(void* const* d_in, const int* in_sizes, int n_in,
                              void* d_out, int out_size, void* d_ws, size_t ws_size,
                              hipStream_t stream) {
    const float* x      = (const float*)d_in[0];
    const float* w_attn = (const float*)d_in[1];
    const float* b_attn = (const float*)d_in[2];
    const float* w_proj = (const float*)d_in[3];
    const float* b_proj = (const float*)d_in[4];
    float* out = (float*)d_out;

    constexpr int Bb = 4, T = 2048, C = 1024;
    constexpr int M = Bb * T;   // 8192

    // workspace layout (bf16 elements): ~92 MB total
    ushort* xb  = (ushort*)d_ws;                    // M*C
    ushort* waT = xb  + (size_t)M * C;              // 3C x C
    ushort* wpT = waT + (size_t)3 * C * C;          // C x C
    ushort* qbf = wpT + (size_t)C * C;              // M x C      (Q only)
    ushort* kpk = qbf + (size_t)M * C;              // 64 bh x T x 64  (K packed)
    ushort* vt  = kpk + (size_t)64 * T * 64;        // 64 bh x 64 x T  (V^T)
    ushort* ao  = vt  + (size_t)64 * 64 * T;        // M x C

    k_prep<<<12288, 256, 0, stream>>>(x, xb, w_attn, waT, w_proj, wpT);
    k_gemm_qkv<<<dim3(3 * C / 128, M / 128), 256, 0, stream>>>(xb, waT, b_attn, qbf, kpk, vt);
    k_attn<<<dim3(8, Bb * 16), 512, 0, stream>>>(qbf, kpk, vt, ao);
    k_gemm_bt<<<dim3(C / 128, M / 128), 256, 0, stream>>>(ao, wpT, b_proj, out, M, C, C);
}

// Round 13
// 234.719 us; speedup vs baseline: 1.0903x; 1.0903x over previous
//
#include <hip/hip_runtime.h>

#define AS1 __attribute__((address_space(1)))
#define AS3 __attribute__((address_space(3)))

using bf16x8  = __attribute__((ext_vector_type(8))) __bf16;
using floatx4 = __attribute__((ext_vector_type(4))) float;

#define SCQ 0.18033688f   // (1/sqrt(64)) * log2(e), folded into Q weights/bias

__device__ inline ushort f2b(float f) {
    __bf16 h = (__bf16)f;
    return __builtin_bit_cast(ushort, h);
}

// raw v_exp_f32 (2^x). Scores are O(+-20): no denorm/overflow handling needed.
__device__ inline float fexp2(float x) {
    float r;
    asm("v_exp_f32 %0, %1" : "=v"(r) : "v"(x));
    return r;
}

// packed f32x2 -> bf16x2 (lo = src0, hi = src1)
__device__ inline unsigned cvtpk_bf16(float lo, float hi) {
    unsigned r;
    asm("v_cvt_pk_bf16_f32 %0, %1, %2" : "=v"(r) : "v"(lo), "v"(hi));
    return r;
}
// a[32:63] <-> b[0:31]
__device__ inline void plswap32(unsigned& a, unsigned& b) {
    asm("v_permlane32_swap_b32 %0, %1" : "+v"(a), "+v"(b));
}
// a[16:31] <-> b[0:15], a[48:63] <-> b[32:47]
__device__ inline void plswap16(unsigned& a, unsigned& b) {
    asm("v_permlane16_swap_b32 %0, %1" : "+v"(a), "+v"(b));
}

// raw barriers for the attn pipeline (no implicit vmcnt(0) drain)
#define BARRIER_A() asm volatile("s_waitcnt lgkmcnt(0)\n\ts_barrier" ::: "memory")
#define BARRIER_B() asm volatile("s_barrier" ::: "memory")

// Build the PV A-fragment (keys base..base+31) from swapped-QK^T exp results.
__device__ inline bf16x8 pack_swap(floatx4 ej0, floatx4 ej1) {
    unsigned x0 = cvtpk_bf16(ej0[0], ej0[1]);
    unsigned x1 = cvtpk_bf16(ej0[2], ej0[3]);
    unsigned y0 = cvtpk_bf16(ej1[0], ej1[1]);
    unsigned y1 = cvtpk_bf16(ej1[2], ej1[3]);
    plswap32(x0, y0); plswap16(x0, y0);
    plswap32(x1, y1); plswap16(x1, y1);
    union { unsigned u[4]; bf16x8 v; } ua;
    ua.u[0] = x0; ua.u[1] = x1; ua.u[2] = y0; ua.u[3] = y1;
    return ua.v;
}

// ---------------- fused prep: f32->bf16 convert of x, + both weight transposes ----------------
__global__ void k_prep(const float* __restrict__ x, ushort* __restrict__ xb,
                       const float* __restrict__ wa, ushort* __restrict__ waT,
                       const float* __restrict__ wp, ushort* __restrict__ wpT)
{
    __shared__ float tile[32][33];
    int blk = blockIdx.x;
    if (blk < 8192) {
        int i = (blk * 256 + threadIdx.x) * 4;
        float4 v = *(const float4*)(x + i);
        ushort4 o;
        o.x = f2b(v.x); o.y = f2b(v.y); o.z = f2b(v.z); o.w = f2b(v.w);
        *(ushort4*)(xb + i) = o;
        return;
    }
    const float* in; ushort* out; int R, Ncol, bx, by; float scale; int scale_cols;
    if (blk < 11264) {
        int idx = blk - 8192;
        in = wa; out = waT; R = 1024; Ncol = 3072;
        bx = idx % 96; by = idx / 96; scale = SCQ; scale_cols = 1024;
    } else {
        int idx = blk - 11264;
        in = wp; out = wpT; R = 1024; Ncol = 1024;
        bx = idx % 32; by = idx / 32; scale = 1.0f; scale_cols = 0;
    }
    int tx = threadIdx.x & 31, ty = threadIdx.x >> 5;   // 32 x 8
    int c0 = bx * 32, r0 = by * 32;
    for (int i = 0; i < 32; i += 8)
        tile[ty + i][tx] = in[(size_t)(r0 + ty + i) * Ncol + c0 + tx];
    __syncthreads();
    for (int i = 0; i < 32; i += 8) {
        int n = c0 + ty + i;
        float v = tile[tx][ty + i];
        if (n < scale_cols) v *= scale;
        out[(size_t)n * R + r0 + tx] = f2b(v);
    }
}

// XCD-aware bijective swizzle of the linear block id (nwg % 8 == 0 for all our grids)
__device__ inline void xcd_swizzle(int& bx, int& by) {
    int gx = gridDim.x, lin = blockIdx.x + gx * blockIdx.y;
    int nwg = gx * gridDim.y;
    int swz = (lin & 7) * (nwg >> 3) + (lin >> 3);
    bx = swz % gx; by = swz / gx;
}

// ---------------- GEMM (proj): round-3 structure (BK=64, 128^2, 1-phase, (256,2)) ----------------
__global__ __launch_bounds__(256, 2) void k_gemm_bt(
    const ushort* __restrict__ A, const ushort* __restrict__ Bt,
    const float* __restrict__ bias, float* __restrict__ outv,
    int M, int N, int K)
{
    __shared__ __align__(16) ushort As[128 * 64];
    __shared__ __align__(16) ushort Bs[128 * 64];
    int tid = threadIdx.x;
    int bxs, bys; xcd_swizzle(bxs, bys);
    int m0 = bys * 128, n0 = bxs * 128;
    int lane = tid & 63;
    int wm = (tid >> 7) * 64;
    int wn = ((tid >> 6) & 1) * 64;
    int lr = lane & 15, quad = lane >> 4;

    floatx4 acc[4][4] = {};
    const ushort* ags[4]; const ushort* bgs[4]; int sdst[4];
    #pragma unroll
    for (int it = 0; it < 4; ++it) {
        int slot = tid + 256 * it;
        int row = slot >> 3, ch = slot & 7;
        ags[it] = A  + (size_t)(m0 + row) * K + ch * 8;
        bgs[it] = Bt + (size_t)(n0 + row) * K + ch * 8;
        sdst[it] = slot * 8;
    }

    for (int kt = 0; kt < K; kt += 64) {
        #pragma unroll
        for (int it = 0; it < 4; ++it) {
            __builtin_amdgcn_global_load_lds((const AS1 unsigned int*)(ags[it] + kt),
                                             (AS3 unsigned int*)&As[sdst[it]], 16, 0, 0);
            __builtin_amdgcn_global_load_lds((const AS1 unsigned int*)(bgs[it] + kt),
                                             (AS3 unsigned int*)&Bs[sdst[it]], 16, 0, 0);
        }
        asm volatile("s_waitcnt vmcnt(0)" ::: "memory");
        __syncthreads();
        bf16x8 af[4][2], bf[4][2];
        #pragma unroll
        for (int i = 0; i < 4; ++i) {
            af[i][0] = *(const bf16x8*)&As[(wm + 16 * i + lr) * 64 + quad * 8];
            af[i][1] = *(const bf16x8*)&As[(wm + 16 * i + lr) * 64 + 32 + quad * 8];
        }
        #pragma unroll
        for (int j = 0; j < 4; ++j) {
            bf[j][0] = *(const bf16x8*)&Bs[(wn + 16 * j + lr) * 64 + quad * 8];
            bf[j][1] = *(const bf16x8*)&Bs[(wn + 16 * j + lr) * 64 + 32 + quad * 8];
        }
        #pragma unroll
        for (int i = 0; i < 4; ++i)
            #pragma unroll
            for (int j = 0; j < 4; ++j) {
                acc[i][j] = __builtin_amdgcn_mfma_f32_16x16x32_bf16(af[i][0], bf[j][0], acc[i][j], 0, 0, 0);
                acc[i][j] = __builtin_amdgcn_mfma_f32_16x16x32_bf16(af[i][1], bf[j][1], acc[i][j], 0, 0, 0);
            }
        __syncthreads();
    }

    #pragma unroll
    for (int j = 0; j < 4; ++j) {
        int col = n0 + wn + 16 * j + lr;
        float bv = bias[col];
        #pragma unroll
        for (int i = 0; i < 4; ++i) {
            int row = m0 + wm + 16 * i + quad * 4;
            #pragma unroll
            for (int r = 0; r < 4; ++r)
                outv[(size_t)(row + r) * N + col] = acc[i][j][r] + bv;
        }
    }
}

// ---------------- QKV GEMM: round-3 structure (BK=64, 128^2, 1-phase, (256,2)) ----------------
// Epilogue routes: Q cols (0..1023)    -> qb[row][1024]           (row-major, Q only)
//                  K cols (1024..2047) -> kpk[bh][t][64] (packed) — contiguous 16KB/tile for attn
//                  V cols (2048..3071) -> vt[bh][d][2048] (transposed, as before)
__global__ __launch_bounds__(256, 2) void k_gemm_qkv(
    const ushort* __restrict__ A, const ushort* __restrict__ Bt,
    const float* __restrict__ bias, ushort* __restrict__ qb,
    ushort* __restrict__ kpk, ushort* __restrict__ vt)
{
    constexpr int K = 1024;
    __shared__ __align__(16) ushort As[128 * 64];
    __shared__ __align__(16) ushort Bs[128 * 64];
    int tid = threadIdx.x;
    int bxs, bys; xcd_swizzle(bxs, bys);
    int m0 = bys * 128, n0 = bxs * 128;
    int lane = tid & 63;
    int wm = (tid >> 7) * 64;
    int wn = ((tid >> 6) & 1) * 64;
    int lr = lane & 15, quad = lane >> 4;

    floatx4 acc[4][4] = {};
    const ushort* ags[4]; const ushort* bgs[4]; int sdst[4];
    #pragma unroll
    for (int it = 0; it < 4; ++it) {
        int slot = tid + 256 * it;
        int row = slot >> 3, ch = slot & 7;
        ags[it] = A  + (size_t)(m0 + row) * K + ch * 8;
        bgs[it] = Bt + (size_t)(n0 + row) * K + ch * 8;
        sdst[it] = slot * 8;
    }

    for (int kt = 0; kt < K; kt += 64) {
        #pragma unroll
        for (int it = 0; it < 4; ++it) {
            __builtin_amdgcn_global_load_lds((const AS1 unsigned int*)(ags[it] + kt),
                                             (AS3 unsigned int*)&As[sdst[it]], 16, 0, 0);
            __builtin_amdgcn_global_load_lds((const AS1 unsigned int*)(bgs[it] + kt),
                                             (AS3 unsigned int*)&Bs[sdst[it]], 16, 0, 0);
        }
        asm volatile("s_waitcnt vmcnt(0)" ::: "memory");
        __syncthreads();
        bf16x8 af[4][2], bf[4][2];
        #pragma unroll
        for (int i = 0; i < 4; ++i) {
            af[i][0] = *(const bf16x8*)&As[(wm + 16 * i + lr) * 64 + quad * 8];
            af[i][1] = *(const bf16x8*)&As[(wm + 16 * i + lr) * 64 + 32 + quad * 8];
        }
        #pragma unroll
        for (int j = 0; j < 4; ++j) {
            bf[j][0] = *(const bf16x8*)&Bs[(wn + 16 * j + lr) * 64 + quad * 8];
            bf[j][1] = *(const bf16x8*)&Bs[(wn + 16 * j + lr) * 64 + 32 + quad * 8];
        }
        #pragma unroll
        for (int i = 0; i < 4; ++i)
            #pragma unroll
            for (int j = 0; j < 4; ++j) {
                acc[i][j] = __builtin_amdgcn_mfma_f32_16x16x32_bf16(af[i][0], bf[j][0], acc[i][j], 0, 0, 0);
                acc[i][j] = __builtin_amdgcn_mfma_f32_16x16x32_bf16(af[i][1], bf[j][1], acc[i][j], 0, 0, 0);
            }
        __syncthreads();
    }

    int bb = m0 >> 11;   // batch index (blocks are 128-row, T=2048-aligned)
    #pragma unroll
    for (int j = 0; j < 4; ++j) {
        int col = n0 + wn + 16 * j + lr;
        float bv = bias[col];
        if (col < 1024) {
            bv *= SCQ;
            #pragma unroll
            for (int i = 0; i < 4; ++i) {
                int row = m0 + wm + 16 * i + quad * 4;
                #pragma unroll
                for (int r = 0; r < 4; ++r)
                    qb[(size_t)(row + r) * 1024 + col] = f2b(acc[i][j][r] + bv);
            }
        } else if (col < 2048) {
            int h = (col - 1024) >> 6, d = (col - 1024) & 63;
            ushort* kbase = kpk + ((size_t)(bb * 16 + h) * 2048) * 64 + d;
            #pragma unroll
            for (int i = 0; i < 4; ++i) {
                int t0 = (m0 + wm + 16 * i + quad * 4) & 2047;
                #pragma unroll
                for (int r = 0; r < 4; ++r)
                    kbase[(size_t)(t0 + r) * 64] = f2b(acc[i][j][r] + bv);
            }
        } else {
            int h = (col - 2048) >> 6, d = (col - 2048) & 63;
            ushort* vbase = vt + ((size_t)(bb * 16 + h) * 64 + d) * 2048;
            #pragma unroll
            for (int i = 0; i < 4; ++i) {
                int t0 = (m0 + wm + 16 * i + quad * 4) & 2047;
                ushort4 pk;
                ((ushort*)&pk)[0] = f2b(acc[i][j][0] + bv);
                ((ushort*)&pk)[1] = f2b(acc[i][j][1] + bv);
                ((ushort*)&pk)[2] = f2b(acc[i][j][2] + bv);
                ((ushort*)&pk)[3] = f2b(acc[i][j][3] + bv);
                *(ushort4*)&vbase[t0] = pk;
            }
        }
    }
}

// ---------------- causal flash attention (merged-2, raw barriers, packed K/V) ----------------
__device__ __forceinline__ void attn_tile(
    const ushort* __restrict__ Kb, const ushort* __restrict__ Vb,
    bf16x8 aq0, bf16x8 aq1, bf16x8 ones,
    floatx4 (&o)[4], floatx4& lacc,
    int kt, int ktd, int qrow, int lr, int quad, int c0, int c1)
{
    floatx4 s[4];
    __builtin_amdgcn_s_setprio(1);
    #pragma unroll
    for (int j = 0; j < 4; ++j) {
        const ushort* kr = &Kb[(16 * j + lr) * 64];
        bf16x8 bk0 = *(const bf16x8*)(kr + c0);
        bf16x8 bk1 = *(const bf16x8*)(kr + c1);
        floatx4 z = {};
        s[j] = __builtin_amdgcn_mfma_f32_16x16x32_bf16(bk0, aq0, z, 0, 0, 0);
        s[j] = __builtin_amdgcn_mfma_f32_16x16x32_bf16(bk1, aq1, s[j], 0, 0, 0);
    }
    __builtin_amdgcn_s_setprio(0);
    floatx4 e[4];
    if (kt == ktd) {
        int qa = qrow + lr;
        #pragma unroll
        for (int j = 0; j < 4; ++j)
            #pragma unroll
            for (int r = 0; r < 4; ++r)
                e[j][r] = ((kt * 64 + 16 * j + quad * 4 + r) > qa) ? 0.f : fexp2(s[j][r]);
    } else {
        #pragma unroll
        for (int j = 0; j < 4; ++j)
            #pragma unroll
            for (int r = 0; r < 4; ++r)
                e[j][r] = fexp2(s[j][r]);
    }
    bf16x8 ap0 = pack_swap(e[0], e[1]);
    bf16x8 ap1 = pack_swap(e[2], e[3]);
    __builtin_amdgcn_s_setprio(1);
    lacc = __builtin_amdgcn_mfma_f32_16x16x32_bf16(ap0, ones, lacc, 0, 0, 0);
    lacc = __builtin_amdgcn_mfma_f32_16x16x32_bf16(ap1, ones, lacc, 0, 0, 0);
    #pragma unroll
    for (int jd = 0; jd < 4; ++jd) {
        const ushort* vr = &Vb[(16 * jd + lr) * 64];
        bf16x8 bv0 = *(const bf16x8*)(vr + c0);
        bf16x8 bv1 = *(const bf16x8*)(vr + c1);
        o[jd] = __builtin_amdgcn_mfma_f32_16x16x32_bf16(ap0, bv0, o[jd], 0, 0, 0);
        o[jd] = __builtin_amdgcn_mfma_f32_16x16x32_bf16(ap1, bv1, o[jd], 0, 0, 0);
    }
    __builtin_amdgcn_s_setprio(0);
}

__global__ __launch_bounds__(512, 4) void k_attn(const ushort* __restrict__ qb,
                                                 const ushort* __restrict__ kpk,
                                                 const ushort* __restrict__ vt,
                                                 ushort* __restrict__ out)
{
    constexpr int T = 2048, C = 1024;
    __shared__ __align__(16) ushort Ks[4][64 * 64];
    __shared__ __align__(16) ushort Vs[4][64 * 64];
    int tid = threadIdx.x;
    int lane = tid & 63, wave = tid >> 6;
    int lr = lane & 15, quad = lane >> 4, lk = quad * 8;

    int lin = blockIdx.x + 8 * blockIdx.y;             // grid (8, 64)
    int qt  = lin >> 6;                                // 0..7
    int bh  = lin & 63;
    int b = bh >> 4, h = bh & 15;
    const ushort* kg0 = kpk + (size_t)bh * T * 64;     // [t][d] packed per head
    const ushort* vg0 = vt + (size_t)bh * 64 * T;      // [d][t] packed per head

    int srow = tid >> 3;                     // key (K) / dim (V)
    int sg   = (tid & 7) ^ (srow & 7);       // XOR-swizzled source chunk
    int sdst = tid * 8;                      // linear LDS dest
    const ushort* kgs = kg0 + (size_t)srow * 64 + sg * 8;
    const ushort* vgs = vg0 + (size_t)srow * T + sg * 8;

    bf16x8 ones;
    #pragma unroll
    for (int i = 0; i < 8; ++i) ones[i] = (__bf16)1.0f;
    int c0 = (quad ^ (lr & 7)) * 8;
    int c1 = ((4 + quad) ^ (lr & 7)) * 8;

    int qtA = qt, qtB = 15 - qt;
    int qrowA = qtA * 128 + wave * 16;
    int qrowB = qtB * 128 + wave * 16;
    int ktdA = qrowA >> 6, ktdB = qrowB >> 6;
    const ushort* qpA = qb + ((size_t)(b * T + qrowA + lr)) * 1024 + h * 64;
    const ushort* qpB = qb + ((size_t)(b * T + qrowB + lr)) * 1024 + h * 64;
    bf16x8 aqA0 = *(const bf16x8*)(qpA + lk);
    bf16x8 aqA1 = *(const bf16x8*)(qpA + 32 + lk);
    bf16x8 aqB0 = *(const bf16x8*)(qpB + lk);
    bf16x8 aqB1 = *(const bf16x8*)(qpB + 32 + lk);
    floatx4 oA[4] = {}, oB[4] = {};
    floatx4 laccA = {}, laccB = {};
    int ktmax = 2 * qtB + 1;

    #pragma unroll
    for (int p = 0; p < 3; ++p) {
        __builtin_amdgcn_global_load_lds((const AS1 unsigned int*)(kgs + (size_t)p * 64 * 64),
                                         (AS3 unsigned int*)&Ks[p][sdst], 16, 0, 0);
        __builtin_amdgcn_global_load_lds((const AS1 unsigned int*)(vgs + p * 64),
                                         (AS3 unsigned int*)&Vs[p][sdst], 16, 0, 0);
    }

    for (int kt = 0; kt <= ktmax; ++kt) {
        BARRIER_A();
        if (kt + 3 <= ktmax) {
            int bidx = (kt + 3) & 3;
            __builtin_amdgcn_global_load_lds((const AS1 unsigned int*)(kgs + (size_t)(kt + 3) * 64 * 64),
                                             (AS3 unsigned int*)&Ks[bidx][sdst], 16, 0, 0);
            __builtin_amdgcn_global_load_lds((const AS1 unsigned int*)(vgs + (kt + 3) * 64),
                                             (AS3 unsigned int*)&Vs[bidx][sdst], 16, 0, 0);
            asm volatile("s_waitcnt vmcnt(6)" ::: "memory");
        } else if (kt + 2 <= ktmax) {
            asm volatile("s_waitcnt vmcnt(4)" ::: "memory");
        } else if (kt + 1 <= ktmax) {
            asm volatile("s_waitcnt vmcnt(2)" ::: "memory");
        } else {
            asm volatile("s_waitcnt vmcnt(0)" ::: "memory");
        }
        BARRIER_B();

        const ushort* Kb = Ks[kt & 3];
        const ushort* Vb = Vs[kt & 3];
        if (kt <= ktdB)
            attn_tile(Kb, Vb, aqB0, aqB1, ones, oB, laccB, kt, ktdB, qrowB, lr, quad, c0, c1);
        if (kt <= ktdA)
            attn_tile(Kb, Vb, aqA0, aqA1, ones, oA, laccA, kt, ktdA, qrowA, lr, quad, c0, c1);
    }

    #pragma unroll
    for (int r = 0; r < 4; ++r) {
        float invA = 1.0f / laccA[r];
        float invB = 1.0f / laccB[r];
        int rowA = b * T + qrowA + quad * 4 + r;
        int rowB = b * T + qrowB + quad * 4 + r;
        #pragma unroll
        for (int jd = 0; jd < 4; ++jd) {
            out[(size_t)rowA * C + h * 64 + 16 * jd + lr] = f2b(oA[jd][r] * invA);
            out[(size_t)rowB * C + h * 64 + 16 * jd + lr] = f2b(oB[jd][r] * invB);
        }
    }
}

extern "C" void kernel_launch(void* const* d_in, const int* in_sizes, int n_in,
                              void* d_out, int out_size, void* d_ws, size_t ws_size,
                              hipStream_t stream) {
    const float* x      = (const float*)d_in[0];
    const float* w_attn = (const float*)d_in[1];
    const float* b_attn = (const float*)d_in[2];
    const float* w_proj = (const float*)d_in[3];
    const float* b_proj = (const float*)d_in[4];
    float* out = (float*)d_out;

    constexpr int Bb = 4, T = 2048, C = 1024;
    constexpr int M = Bb * T;   // 8192

    // workspace layout (bf16 elements): ~92 MB total
    ushort* xb  = (ushort*)d_ws;                    // M*C
    ushort* waT = xb  + (size_t)M * C;              // 3C x C
    ushort* wpT = waT + (size_t)3 * C * C;          // C x C
    ushort* qbf = wpT + (size_t)C * C;              // M x C      (Q only)
    ushort* kpk = qbf + (size_t)M * C;              // 64 bh x T x 64  (K packed)
    ushort* vt  = kpk + (size_t)64 * T * 64;        // 64 bh x 64 x T  (V^T)
    ushort* ao  = vt  + (size_t)64 * 64 * T;        // M x C

    k_prep<<<12288, 256, 0, stream>>>(x, xb, w_attn, waT, w_proj, wpT);
    k_gemm_qkv<<<dim3(3 * C / 128, M / 128), 256, 0, stream>>>(xb, waT, b_attn, qbf, kpk, vt);
    k_attn<<<dim3(8, Bb * 16), 512, 0, stream>>>(qbf, kpk, vt, ao);
    k_gemm_bt<<<dim3(C / 128, M / 128), 256, 0, stream>>>(ao, wpT, b_proj, out, M, C, C);
}

// Round 14
// 234.092 us; speedup vs baseline: 1.0933x; 1.0027x over previous
//
#include <hip/hip_runtime.h>

#define AS1 __attribute__((address_space(1)))
#define AS3 __attribute__((address_space(3)))

using bf16x8  = __attribute__((ext_vector_type(8))) __bf16;
using floatx4 = __attribute__((ext_vector_type(4))) float;

#define SCQ 0.18033688f   // (1/sqrt(64)) * log2(e), folded into Q weights/bias

__device__ inline ushort f2b(float f) {
    __bf16 h = (__bf16)f;
    return __builtin_bit_cast(ushort, h);
}

// raw v_exp_f32 (2^x). Scores are O(+-20): no denorm/overflow handling needed.
__device__ inline float fexp2(float x) {
    float r;
    asm("v_exp_f32 %0, %1" : "=v"(r) : "v"(x));
    return r;
}

// packed f32x2 -> bf16x2 (lo = src0, hi = src1)
__device__ inline unsigned cvtpk_bf16(float lo, float hi) {
    unsigned r;
    asm("v_cvt_pk_bf16_f32 %0, %1, %2" : "=v"(r) : "v"(lo), "v"(hi));
    return r;
}
// a[32:63] <-> b[0:31]
__device__ inline void plswap32(unsigned& a, unsigned& b) {
    asm("v_permlane32_swap_b32 %0, %1" : "+v"(a), "+v"(b));
}
// a[16:31] <-> b[0:15], a[48:63] <-> b[32:47]
__device__ inline void plswap16(unsigned& a, unsigned& b) {
    asm("v_permlane16_swap_b32 %0, %1" : "+v"(a), "+v"(b));
}

// raw barriers for the attn pipeline (no implicit vmcnt(0) drain)
#define BARRIER_A() asm volatile("s_waitcnt lgkmcnt(0)\n\ts_barrier" ::: "memory")
#define BARRIER_B() asm volatile("s_barrier" ::: "memory")

// Build the PV A-fragment (keys base..base+31) from swapped-QK^T exp results.
__device__ inline bf16x8 pack_swap(floatx4 ej0, floatx4 ej1) {
    unsigned x0 = cvtpk_bf16(ej0[0], ej0[1]);
    unsigned x1 = cvtpk_bf16(ej0[2], ej0[3]);
    unsigned y0 = cvtpk_bf16(ej1[0], ej1[1]);
    unsigned y1 = cvtpk_bf16(ej1[2], ej1[3]);
    plswap32(x0, y0); plswap16(x0, y0);
    plswap32(x1, y1); plswap16(x1, y1);
    union { unsigned u[4]; bf16x8 v; } ua;
    ua.u[0] = x0; ua.u[1] = x1; ua.u[2] = y0; ua.u[3] = y1;
    return ua.v;
}

// ---------------- fused prep: f32->bf16 convert of x, + both weight transposes ----------------
__global__ void k_prep(const float* __restrict__ x, ushort* __restrict__ xb,
                       const float* __restrict__ wa, ushort* __restrict__ waT,
                       const float* __restrict__ wp, ushort* __restrict__ wpT)
{
    __shared__ float tile[32][33];
    int blk = blockIdx.x;
    if (blk < 8192) {
        int i = (blk * 256 + threadIdx.x) * 4;
        float4 v = *(const float4*)(x + i);
        ushort4 o;
        o.x = f2b(v.x); o.y = f2b(v.y); o.z = f2b(v.z); o.w = f2b(v.w);
        *(ushort4*)(xb + i) = o;
        return;
    }
    const float* in; ushort* out; int R, Ncol, bx, by; float scale; int scale_cols;
    if (blk < 11264) {
        int idx = blk - 8192;
        in = wa; out = waT; R = 1024; Ncol = 3072;
        bx = idx % 96; by = idx / 96; scale = SCQ; scale_cols = 1024;
    } else {
        int idx = blk - 11264;
        in = wp; out = wpT; R = 1024; Ncol = 1024;
        bx = idx % 32; by = idx / 32; scale = 1.0f; scale_cols = 0;
    }
    int tx = threadIdx.x & 31, ty = threadIdx.x >> 5;   // 32 x 8
    int c0 = bx * 32, r0 = by * 32;
    for (int i = 0; i < 32; i += 8)
        tile[ty + i][tx] = in[(size_t)(r0 + ty + i) * Ncol + c0 + tx];
    __syncthreads();
    for (int i = 0; i < 32; i += 8) {
        int n = c0 + ty + i;
        float v = tile[tx][ty + i];
        if (n < scale_cols) v *= scale;
        out[(size_t)n * R + r0 + tx] = f2b(v);
    }
}

// XCD-aware bijective swizzle of the linear block id (nwg % 8 == 0 for all our grids)
__device__ inline void xcd_swizzle(int& bx, int& by) {
    int gx = gridDim.x, lin = blockIdx.x + gx * blockIdx.y;
    int nwg = gx * gridDim.y;
    int swz = (lin & 7) * (nwg >> 3) + (lin >> 3);
    bx = swz % gx; by = swz / gx;
}

// ---------------- GEMM (proj): round-3 structure (BK=64, 128^2, 1-phase) ----------------
// (256,3): 3 blocks/CU target — reg cap 512/3≈170 > current 140 (76V+64A), so
// codegen unchanged (unlike r8's (256,4) which forced V<=64); occupancy 2->3 blocks.
__global__ __launch_bounds__(256, 3) void k_gemm_bt(
    const ushort* __restrict__ A, const ushort* __restrict__ Bt,
    const float* __restrict__ bias, float* __restrict__ outv,
    int M, int N, int K)
{
    __shared__ __align__(16) ushort As[128 * 64];
    __shared__ __align__(16) ushort Bs[128 * 64];
    int tid = threadIdx.x;
    int bxs, bys; xcd_swizzle(bxs, bys);
    int m0 = bys * 128, n0 = bxs * 128;
    int lane = tid & 63;
    int wm = (tid >> 7) * 64;
    int wn = ((tid >> 6) & 1) * 64;
    int lr = lane & 15, quad = lane >> 4;

    floatx4 acc[4][4] = {};
    const ushort* ags[4]; const ushort* bgs[4]; int sdst[4];
    #pragma unroll
    for (int it = 0; it < 4; ++it) {
        int slot = tid + 256 * it;
        int row = slot >> 3, ch = slot & 7;
        ags[it] = A  + (size_t)(m0 + row) * K + ch * 8;
        bgs[it] = Bt + (size_t)(n0 + row) * K + ch * 8;
        sdst[it] = slot * 8;
    }

    for (int kt = 0; kt < K; kt += 64) {
        #pragma unroll
        for (int it = 0; it < 4; ++it) {
            __builtin_amdgcn_global_load_lds((const AS1 unsigned int*)(ags[it] + kt),
                                             (AS3 unsigned int*)&As[sdst[it]], 16, 0, 0);
            __builtin_amdgcn_global_load_lds((const AS1 unsigned int*)(bgs[it] + kt),
                                             (AS3 unsigned int*)&Bs[sdst[it]], 16, 0, 0);
        }
        asm volatile("s_waitcnt vmcnt(0)" ::: "memory");
        __syncthreads();
        bf16x8 af[4][2], bf[4][2];
        #pragma unroll
        for (int i = 0; i < 4; ++i) {
            af[i][0] = *(const bf16x8*)&As[(wm + 16 * i + lr) * 64 + quad * 8];
            af[i][1] = *(const bf16x8*)&As[(wm + 16 * i + lr) * 64 + 32 + quad * 8];
        }
        #pragma unroll
        for (int j = 0; j < 4; ++j) {
            bf[j][0] = *(const bf16x8*)&Bs[(wn + 16 * j + lr) * 64 + quad * 8];
            bf[j][1] = *(const bf16x8*)&Bs[(wn + 16 * j + lr) * 64 + 32 + quad * 8];
        }
        #pragma unroll
        for (int i = 0; i < 4; ++i)
            #pragma unroll
            for (int j = 0; j < 4; ++j) {
                acc[i][j] = __builtin_amdgcn_mfma_f32_16x16x32_bf16(af[i][0], bf[j][0], acc[i][j], 0, 0, 0);
                acc[i][j] = __builtin_amdgcn_mfma_f32_16x16x32_bf16(af[i][1], bf[j][1], acc[i][j], 0, 0, 0);
            }
        __syncthreads();
    }

    #pragma unroll
    for (int j = 0; j < 4; ++j) {
        int col = n0 + wn + 16 * j + lr;
        float bv = bias[col];
        #pragma unroll
        for (int i = 0; i < 4; ++i) {
            int row = m0 + wm + 16 * i + quad * 4;
            #pragma unroll
            for (int r = 0; r < 4; ++r)
                outv[(size_t)(row + r) * N + col] = acc[i][j][r] + bv;
        }
    }
}

// ---------------- QKV GEMM: round-3 structure (BK=64, 128^2, 1-phase, (256,3)) ----------------
// Epilogue routes: Q cols (0..1023)    -> qb[row][1024]           (row-major, Q only)
//                  K cols (1024..2047) -> kpk[bh][t][64] (packed) — contiguous 16KB/tile for attn
//                  V cols (2048..3071) -> vt[bh][d][2048] (transposed, as before)
__global__ __launch_bounds__(256, 3) void k_gemm_qkv(
    const ushort* __restrict__ A, const ushort* __restrict__ Bt,
    const float* __restrict__ bias, ushort* __restrict__ qb,
    ushort* __restrict__ kpk, ushort* __restrict__ vt)
{
    constexpr int K = 1024;
    __shared__ __align__(16) ushort As[128 * 64];
    __shared__ __align__(16) ushort Bs[128 * 64];
    int tid = threadIdx.x;
    int bxs, bys; xcd_swizzle(bxs, bys);
    int m0 = bys * 128, n0 = bxs * 128;
    int lane = tid & 63;
    int wm = (tid >> 7) * 64;
    int wn = ((tid >> 6) & 1) * 64;
    int lr = lane & 15, quad = lane >> 4;

    floatx4 acc[4][4] = {};
    const ushort* ags[4]; const ushort* bgs[4]; int sdst[4];
    #pragma unroll
    for (int it = 0; it < 4; ++it) {
        int slot = tid + 256 * it;
        int row = slot >> 3, ch = slot & 7;
        ags[it] = A  + (size_t)(m0 + row) * K + ch * 8;
        bgs[it] = Bt + (size_t)(n0 + row) * K + ch * 8;
        sdst[it] = slot * 8;
    }

    for (int kt = 0; kt < K; kt += 64) {
        #pragma unroll
        for (int it = 0; it < 4; ++it) {
            __builtin_amdgcn_global_load_lds((const AS1 unsigned int*)(ags[it] + kt),
                                             (AS3 unsigned int*)&As[sdst[it]], 16, 0, 0);
            __builtin_amdgcn_global_load_lds((const AS1 unsigned int*)(bgs[it] + kt),
                                             (AS3 unsigned int*)&Bs[sdst[it]], 16, 0, 0);
        }
        asm volatile("s_waitcnt vmcnt(0)" ::: "memory");
        __syncthreads();
        bf16x8 af[4][2], bf[4][2];
        #pragma unroll
        for (int i = 0; i < 4; ++i) {
            af[i][0] = *(const bf16x8*)&As[(wm + 16 * i + lr) * 64 + quad * 8];
            af[i][1] = *(const bf16x8*)&As[(wm + 16 * i + lr) * 64 + 32 + quad * 8];
        }
        #pragma unroll
        for (int j = 0; j < 4; ++j) {
            bf[j][0] = *(const bf16x8*)&Bs[(wn + 16 * j + lr) * 64 + quad * 8];
            bf[j][1] = *(const bf16x8*)&Bs[(wn + 16 * j + lr) * 64 + 32 + quad * 8];
        }
        #pragma unroll
        for (int i = 0; i < 4; ++i)
            #pragma unroll
            for (int j = 0; j < 4; ++j) {
                acc[i][j] = __builtin_amdgcn_mfma_f32_16x16x32_bf16(af[i][0], bf[j][0], acc[i][j], 0, 0, 0);
                acc[i][j] = __builtin_amdgcn_mfma_f32_16x16x32_bf16(af[i][1], bf[j][1], acc[i][j], 0, 0, 0);
            }
        __syncthreads();
    }

    int bb = m0 >> 11;   // batch index (blocks are 128-row, T=2048-aligned)
    #pragma unroll
    for (int j = 0; j < 4; ++j) {
        int col = n0 + wn + 16 * j + lr;
        float bv = bias[col];
        if (col < 1024) {
            bv *= SCQ;
            #pragma unroll
            for (int i = 0; i < 4; ++i) {
                int row = m0 + wm + 16 * i + quad * 4;
                #pragma unroll
                for (int r = 0; r < 4; ++r)
                    qb[(size_t)(row + r) * 1024 + col] = f2b(acc[i][j][r] + bv);
            }
        } else if (col < 2048) {
            int h = (col - 1024) >> 6, d = (col - 1024) & 63;
            ushort* kbase = kpk + ((size_t)(bb * 16 + h) * 2048) * 64 + d;
            #pragma unroll
            for (int i = 0; i < 4; ++i) {
                int t0 = (m0 + wm + 16 * i + quad * 4) & 2047;
                #pragma unroll
                for (int r = 0; r < 4; ++r)
                    kbase[(size_t)(t0 + r) * 64] = f2b(acc[i][j][r] + bv);
            }
        } else {
            int h = (col - 2048) >> 6, d = (col - 2048) & 63;
            ushort* vbase = vt + ((size_t)(bb * 16 + h) * 64 + d) * 2048;
            #pragma unroll
            for (int i = 0; i < 4; ++i) {
                int t0 = (m0 + wm + 16 * i + quad * 4) & 2047;
                ushort4 pk;
                ((ushort*)&pk)[0] = f2b(acc[i][j][0] + bv);
                ((ushort*)&pk)[1] = f2b(acc[i][j][1] + bv);
                ((ushort*)&pk)[2] = f2b(acc[i][j][2] + bv);
                ((ushort*)&pk)[3] = f2b(acc[i][j][3] + bv);
                *(ushort4*)&vbase[t0] = pk;
            }
        }
    }
}

// ---------------- causal flash attention (merged-2, raw barriers, packed K/V) ----------------
__device__ __forceinline__ void attn_tile(
    const ushort* __restrict__ Kb, const ushort* __restrict__ Vb,
    bf16x8 aq0, bf16x8 aq1, bf16x8 ones,
    floatx4 (&o)[4], floatx4& lacc,
    int kt, int ktd, int qrow, int lr, int quad, int c0, int c1)
{
    floatx4 s[4];
    __builtin_amdgcn_s_setprio(1);
    #pragma unroll
    for (int j = 0; j < 4; ++j) {
        const ushort* kr = &Kb[(16 * j + lr) * 64];
        bf16x8 bk0 = *(const bf16x8*)(kr + c0);
        bf16x8 bk1 = *(const bf16x8*)(kr + c1);
        floatx4 z = {};
        s[j] = __builtin_amdgcn_mfma_f32_16x16x32_bf16(bk0, aq0, z, 0, 0, 0);
        s[j] = __builtin_amdgcn_mfma_f32_16x16x32_bf16(bk1, aq1, s[j], 0, 0, 0);
    }
    __builtin_amdgcn_s_setprio(0);
    floatx4 e[4];
    if (kt == ktd) {
        int qa = qrow + lr;
        #pragma unroll
        for (int j = 0; j < 4; ++j)
            #pragma unroll
            for (int r = 0; r < 4; ++r)
                e[j][r] = ((kt * 64 + 16 * j + quad * 4 + r) > qa) ? 0.f : fexp2(s[j][r]);
    } else {
        #pragma unroll
        for (int j = 0; j < 4; ++j)
            #pragma unroll
            for (int r = 0; r < 4; ++r)
                e[j][r] = fexp2(s[j][r]);
    }
    bf16x8 ap0 = pack_swap(e[0], e[1]);
    bf16x8 ap1 = pack_swap(e[2], e[3]);
    __builtin_amdgcn_s_setprio(1);
    lacc = __builtin_amdgcn_mfma_f32_16x16x32_bf16(ap0, ones, lacc, 0, 0, 0);
    lacc = __builtin_amdgcn_mfma_f32_16x16x32_bf16(ap1, ones, lacc, 0, 0, 0);
    #pragma unroll
    for (int jd = 0; jd < 4; ++jd) {
        const ushort* vr = &Vb[(16 * jd + lr) * 64];
        bf16x8 bv0 = *(const bf16x8*)(vr + c0);
        bf16x8 bv1 = *(const bf16x8*)(vr + c1);
        o[jd] = __builtin_amdgcn_mfma_f32_16x16x32_bf16(ap0, bv0, o[jd], 0, 0, 0);
        o[jd] = __builtin_amdgcn_mfma_f32_16x16x32_bf16(ap1, bv1, o[jd], 0, 0, 0);
    }
    __builtin_amdgcn_s_setprio(0);
}

__global__ __launch_bounds__(512, 4) void k_attn(const ushort* __restrict__ qb,
                                                 const ushort* __restrict__ kpk,
                                                 const ushort* __restrict__ vt,
                                                 ushort* __restrict__ out)
{
    constexpr int T = 2048, C = 1024;
    __shared__ __align__(16) ushort Ks[4][64 * 64];
    __shared__ __align__(16) ushort Vs[4][64 * 64];
    int tid = threadIdx.x;
    int lane = tid & 63, wave = tid >> 6;
    int lr = lane & 15, quad = lane >> 4, lk = quad * 8;

    int lin = blockIdx.x + 8 * blockIdx.y;             // grid (8, 64)
    int qt  = lin >> 6;                                // 0..7
    int bh  = lin & 63;
    int b = bh >> 4, h = bh & 15;
    const ushort* kg0 = kpk + (size_t)bh * T * 64;     // [t][d] packed per head
    const ushort* vg0 = vt + (size_t)bh * 64 * T;      // [d][t] packed per head

    int srow = tid >> 3;                     // key (K) / dim (V)
    int sg   = (tid & 7) ^ (srow & 7);       // XOR-swizzled source chunk
    int sdst = tid * 8;                      // linear LDS dest
    const ushort* kgs = kg0 + (size_t)srow * 64 + sg * 8;
    const ushort* vgs = vg0 + (size_t)srow * T + sg * 8;

    bf16x8 ones;
    #pragma unroll
    for (int i = 0; i < 8; ++i) ones[i] = (__bf16)1.0f;
    int c0 = (quad ^ (lr & 7)) * 8;
    int c1 = ((4 + quad) ^ (lr & 7)) * 8;

    int qtA = qt, qtB = 15 - qt;
    int qrowA = qtA * 128 + wave * 16;
    int qrowB = qtB * 128 + wave * 16;
    int ktdA = qrowA >> 6, ktdB = qrowB >> 6;
    const ushort* qpA = qb + ((size_t)(b * T + qrowA + lr)) * 1024 + h * 64;
    const ushort* qpB = qb + ((size_t)(b * T + qrowB + lr)) * 1024 + h * 64;
    bf16x8 aqA0 = *(const bf16x8*)(qpA + lk);
    bf16x8 aqA1 = *(const bf16x8*)(qpA + 32 + lk);
    bf16x8 aqB0 = *(const bf16x8*)(qpB + lk);
    bf16x8 aqB1 = *(const bf16x8*)(qpB + 32 + lk);
    floatx4 oA[4] = {}, oB[4] = {};
    floatx4 laccA = {}, laccB = {};
    int ktmax = 2 * qtB + 1;

    #pragma unroll
    for (int p = 0; p < 3; ++p) {
        __builtin_amdgcn_global_load_lds((const AS1 unsigned int*)(kgs + (size_t)p * 64 * 64),
                                         (AS3 unsigned int*)&Ks[p][sdst], 16, 0, 0);
        __builtin_amdgcn_global_load_lds((const AS1 unsigned int*)(vgs + p * 64),
                                         (AS3 unsigned int*)&Vs[p][sdst], 16, 0, 0);
    }

    for (int kt = 0; kt <= ktmax; ++kt) {
        BARRIER_A();
        if (kt + 3 <= ktmax) {
            int bidx = (kt + 3) & 3;
            __builtin_amdgcn_global_load_lds((const AS1 unsigned int*)(kgs + (size_t)(kt + 3) * 64 * 64),
                                             (AS3 unsigned int*)&Ks[bidx][sdst], 16, 0, 0);
            __builtin_amdgcn_global_load_lds((const AS1 unsigned int*)(vgs + (kt + 3) * 64),
                                             (AS3 unsigned int*)&Vs[bidx][sdst], 16, 0, 0);
            asm volatile("s_waitcnt vmcnt(6)" ::: "memory");
        } else if (kt + 2 <= ktmax) {
            asm volatile("s_waitcnt vmcnt(4)" ::: "memory");
        } else if (kt + 1 <= ktmax) {
            asm volatile("s_waitcnt vmcnt(2)" ::: "memory");
        } else {
            asm volatile("s_waitcnt vmcnt(0)" ::: "memory");
        }
        BARRIER_B();

        const ushort* Kb = Ks[kt & 3];
        const ushort* Vb = Vs[kt & 3];
        if (kt <= ktdB)
            attn_tile(Kb, Vb, aqB0, aqB1, ones, oB, laccB, kt, ktdB, qrowB, lr, quad, c0, c1);
        if (kt <= ktdA)
            attn_tile(Kb, Vb, aqA0, aqA1, ones, oA, laccA, kt, ktdA, qrowA, lr, quad, c0, c1);
    }

    #pragma unroll
    for (int r = 0; r < 4; ++r) {
        float invA = 1.0f / laccA[r];
        float invB = 1.0f / laccB[r];
        int rowA = b * T + qrowA + quad * 4 + r;
        int rowB = b * T + qrowB + quad * 4 + r;
        #pragma unroll
        for (int jd = 0; jd < 4; ++jd) {
            out[(size_t)rowA * C + h * 64 + 16 * jd + lr] = f2b(oA[jd][r] * invA);
            out[(size_t)rowB * C + h * 64 + 16 * jd + lr] = f2b(oB[jd][r] * invB);
        }
    }
}

extern "C" void kernel_launch(void* const* d_in, const int* in_sizes, int n_in,
                              void* d_out, int out_size, void* d_ws, size_t ws_size,
                              hipStream_t stream) {
    const float* x      = (const float*)d_in[0];
    const float* w_attn = (const float*)d_in[1];
    const float* b_attn = (const float*)d_in[2];
    const float* w_proj = (const float*)d_in[3];
    const float* b_proj = (const float*)d_in[4];
    float* out = (float*)d_out;

    constexpr int Bb = 4, T = 2048, C = 1024;
    constexpr int M = Bb * T;   // 8192

    // workspace layout (bf16 elements): ~92 MB total
    ushort* xb  = (ushort*)d_ws;                    // M*C
    ushort* waT = xb  + (size_t)M * C;              // 3C x C
    ushort* wpT = waT + (size_t)3 * C * C;          // C x C
    ushort* qbf = wpT + (size_t)C * C;              // M x C      (Q only)
    ushort* kpk = qbf + (size_t)M * C;              // 64 bh x T x 64  (K packed)
    ushort* vt  = kpk + (size_t)64 * T * 64;        // 64 bh x 64 x T  (V^T)
    ushort* ao  = vt  + (size_t)64 * 64 * T;        // M x C

    k_prep<<<12288, 256, 0, stream>>>(x, xb, w_attn, waT, w_proj, wpT);
    k_gemm_qkv<<<dim3(3 * C / 128, M / 128), 256, 0, stream>>>(xb, waT, b_attn, qbf, kpk, vt);
    k_attn<<<dim3(8, Bb * 16), 512, 0, stream>>>(qbf, kpk, vt, ao);
    k_gemm_bt<<<dim3(C / 128, M / 128), 256, 0, stream>>>(ao, wpT, b_proj, out, M, C, C);
}